// Round 8
// baseline (1460.981 us; speedup 1.0000x reference)
//
#include <hip/hip_runtime.h>
#include <hip/hip_fp16.h>

// GCN: 4x GCNConv(relu) -> global_add_pool -> MLP(96->32 relu ->1)
// N=100000 nodes, E=1600000 edges, F=32, H=96, G=2048 graphs.
//
// R8: revert aggregate to R6 shape (TPN=24, uint2 8B lanes, pad8 rows,
// 8-way unroll — measured sweet spot; R4/R7's TPN=12 variants regressed via
// trip-count divergence). NEW: CSR built in degree-sorted node order
// (bucket sort by padded degree) so all rows in a wave have equal trip
// counts -> removes ~26% wasted edge iterations. col/val stay sequential.

#define HIDDEN 96

__device__ inline float4 h4_to_f4(uint2 u) {
    __half2 a = *reinterpret_cast<__half2*>(&u.x);
    __half2 b = *reinterpret_cast<__half2*>(&u.y);
    float2 fa = __half22float2(a), fb = __half22float2(b);
    return make_float4(fa.x, fa.y, fb.x, fb.y);
}

__device__ inline uint2 f4_to_h4(float4 v) {
    __half2 a = __float22half2_rn(make_float2(v.x, v.y));
    __half2 b = __float22half2_rn(make_float2(v.z, v.w));
    uint2 u;
    u.x = *reinterpret_cast<unsigned*>(&a);
    u.y = *reinterpret_cast<unsigned*>(&b);
    return u;
}

__device__ inline int pad8i(int c) { return (c + 7) & ~7; }

__global__ __launch_bounds__(256) void zero_int_kernel(int* p, int n) {
    int i = blockIdx.x * 256 + threadIdx.x;
    if (i < n) p[i] = 0;
}

__global__ __launch_bounds__(256) void zero_kernel(float* p, int n) {
    int i = blockIdx.x * 256 + threadIdx.x;
    if (i < n) p[i] = 0.0f;
}

__global__ __launch_bounds__(256) void cast_h_kernel(const float4* __restrict__ in,
                                                     uint2* __restrict__ out, int n4) {
    int i = blockIdx.x * 256 + threadIdx.x;
    if (i < n4) out[i] = f4_to_h4(in[i]);
}

// in-degree histogram over dst; epos[e] = this edge's slot within its dst row
__global__ __launch_bounds__(256) void deg_pos_kernel(const int* __restrict__ dst,
                                                      int* __restrict__ cnt,
                                                      int* __restrict__ epos, int E) {
    int e = blockIdx.x * 256 + threadIdx.x;
    if (e < E) epos[e] = atomicAdd(&cnt[dst[e]], 1);
}

__global__ __launch_bounds__(256) void dinv_kernel(const int* __restrict__ cnt,
                                                   float* __restrict__ dinv, int n) {
    int i = blockIdx.x * 256 + threadIdx.x;
    if (i < n) dinv[i] = rsqrtf((float)(cnt[i] + 1));
}

// ---- degree bucket sort (64 buckets of padded-degree/8) ----
__global__ __launch_bounds__(256) void bucket_kernel(const int* __restrict__ cnt,
                                                     int* __restrict__ hist,
                                                     int* __restrict__ mypos, int N) {
    int i = blockIdx.x * 256 + threadIdx.x;
    if (i >= N) return;
    int k = min(pad8i(cnt[i]) >> 3, 63);
    mypos[i] = atomicAdd(&hist[k], 1);
}

// exclusive scan of hist[0..64) in one wave
__global__ __launch_bounds__(64) void hist_scan_kernel(const int* __restrict__ hist,
                                                       int* __restrict__ base) {
    int tid = threadIdx.x;
    int h = hist[tid];
    int v = h;
    for (int off = 1; off < 64; off <<= 1) {
        int t = __shfl_up(v, off);
        if (tid >= off) v += t;
    }
    base[tid] = v - h;  // exclusive
}

__global__ __launch_bounds__(256) void rank_kernel(const int* __restrict__ cnt,
                                                   const int* __restrict__ base,
                                                   const int* __restrict__ mypos,
                                                   int* __restrict__ rank,
                                                   int* __restrict__ perm, int N) {
    int i = blockIdx.x * 256 + threadIdx.x;
    if (i >= N) return;
    int k = min(pad8i(cnt[i]) >> 3, 63);
    int r = base[k] + mypos[i];
    rank[i] = r;
    perm[r] = i;
}

// ---- 3-phase exclusive scan of pad8(cnt[perm[0..N)]) -> rowptr_s ----
__global__ __launch_bounds__(256) void scan_reduce_kernel(const int* __restrict__ cnt,
                                                          const int* __restrict__ perm,
                                                          int* __restrict__ bsum, int N) {
    __shared__ int s[256];
    int b = blockIdx.x, tid = threadIdx.x;
    int basei = b * 1024;
    int v = 0;
    for (int j = tid; j < 1024; j += 256) {
        int i = basei + j;
        v += (i < N) ? pad8i(cnt[perm[i]]) : 0;
    }
    s[tid] = v;
    __syncthreads();
    for (int off = 128; off > 0; off >>= 1) {
        if (tid < off) s[tid] += s[tid + off];
        __syncthreads();
    }
    if (tid == 0) bsum[b] = s[0];
}

__global__ __launch_bounds__(128) void scan_bsum_kernel(int* __restrict__ bsum, int nb) {
    __shared__ int s[128];
    int tid = threadIdx.x;
    int v = (tid < nb) ? bsum[tid] : 0;
    s[tid] = v;
    __syncthreads();
    for (int off = 1; off < 128; off <<= 1) {
        int t = (tid >= off) ? s[tid - off] : 0;
        __syncthreads();
        s[tid] += t;
        __syncthreads();
    }
    if (tid < nb) bsum[tid] = s[tid] - v;  // exclusive
}

__global__ __launch_bounds__(256) void scan_write_kernel(const int* __restrict__ cnt,
                                                         const int* __restrict__ perm,
                                                         const int* __restrict__ bsum,
                                                         int* __restrict__ rowptr, int N) {
    __shared__ int ts[256];
    int b = blockIdx.x, tid = threadIdx.x;
    int basei = b * 1024 + tid * 4;
    int v0 = (basei + 0 < N) ? pad8i(cnt[perm[basei + 0]]) : 0;
    int v1 = (basei + 1 < N) ? pad8i(cnt[perm[basei + 1]]) : 0;
    int v2 = (basei + 2 < N) ? pad8i(cnt[perm[basei + 2]]) : 0;
    int v3 = (basei + 3 < N) ? pad8i(cnt[perm[basei + 3]]) : 0;
    int sum = v0 + v1 + v2 + v3;
    ts[tid] = sum;
    __syncthreads();
    for (int off = 1; off < 256; off <<= 1) {
        int t = (tid >= off) ? ts[tid - off] : 0;
        __syncthreads();
        ts[tid] += t;
        __syncthreads();
    }
    int excl = bsum[b] + ts[tid] - sum;
    if (basei + 0 <= N) rowptr[basei + 0] = excl;
    if (basei + 1 <= N) rowptr[basei + 1] = excl + v0;
    if (basei + 2 <= N) rowptr[basei + 2] = excl + v0 + v1;
    if (basei + 3 <= N) rowptr[basei + 3] = excl + v0 + v1 + v2;
}

// Fill CSR slots in degree-sorted row order.
__global__ __launch_bounds__(256) void fill_csr_kernel(const int* __restrict__ src,
                                                       const int* __restrict__ dst,
                                                       const int* __restrict__ epos,
                                                       const int* __restrict__ rank,
                                                       const float* __restrict__ dinv,
                                                       const int* __restrict__ rowptr,
                                                       int* __restrict__ col,
                                                       float* __restrict__ val, int E) {
    int e = blockIdx.x * 256 + threadIdx.x;
    if (e >= E) return;
    int s = src[e];
    int d = dst[e];
    int idx = rowptr[rank[d]] + epos[e];
    col[idx] = s;
    val[idx] = dinv[s] * dinv[d];
}

// Y[n x 96] = act(X[n x K]) @ W[K x 96] (+ b).  W in LDS, fp16 in/out.
template <int K, bool RELU, bool BIAS>
__global__ __launch_bounds__(256) void gemm_kernel(const uint2* __restrict__ X,
                                                   const float* __restrict__ W,
                                                   const float* __restrict__ b,
                                                   uint2* __restrict__ Y, int n) {
    __shared__ float wlds[K * HIDDEN];
    for (int idx = threadIdx.x; idx < K * HIDDEN; idx += 256) wlds[idx] = W[idx];
    __syncthreads();

    int row = blockIdx.x * 256 + threadIdx.x;
    if (row >= n) return;

    float4 acc[24];
#pragma unroll
    for (int j = 0; j < 24; j++) acc[j] = make_float4(0.f, 0.f, 0.f, 0.f);

    const float4* wl4 = reinterpret_cast<const float4*>(wlds);
    const uint2* xrow = X + (size_t)row * (K / 4);

    for (int k0 = 0; k0 < K; k0 += 4) {
        float4 xv = h4_to_f4(xrow[k0 >> 2]);
        if (RELU) {
            xv.x = fmaxf(xv.x, 0.f); xv.y = fmaxf(xv.y, 0.f);
            xv.z = fmaxf(xv.z, 0.f); xv.w = fmaxf(xv.w, 0.f);
        }
#pragma unroll
        for (int kk = 0; kk < 4; kk++) {
            float xs = (kk == 0) ? xv.x : (kk == 1) ? xv.y : (kk == 2) ? xv.z : xv.w;
#pragma unroll
            for (int j = 0; j < 24; j++) {
                float4 w = wl4[(k0 + kk) * 24 + j];
                acc[j].x += xs * w.x;
                acc[j].y += xs * w.y;
                acc[j].z += xs * w.z;
                acc[j].w += xs * w.w;
            }
        }
    }

    uint2* y2 = Y + (size_t)row * 24;
#pragma unroll
    for (int j = 0; j < 24; j++) {
        if (BIAS) {
            float4 bb = reinterpret_cast<const float4*>(b)[j];
            acc[j].x += bb.x; acc[j].y += bb.y; acc[j].z += bb.z; acc[j].w += bb.w;
        }
        y2[j] = f4_to_h4(acc[j]);
    }
}

// Degree-sorted aggregate: sorted position j -> node i = perm[j].
// out[i] = dinv[i]^2*xw[i] (+ b) + sum_e val[e]*xw[col[e]], xw fp16.
// TPN threads/node (4 feats = uint2 8B per lane), rows padded to 8,
// 8-way unroll. fp32 accumulate. POOL: atomicAdd relu into gpool[batch[i]].
template <int TPN, bool POOL, bool BIAS>
__global__ __launch_bounds__(256) void aggregate_kernel(const uint2* __restrict__ xwh,
                                                        const int* __restrict__ rowptr,
                                                        const int* __restrict__ col,
                                                        const float* __restrict__ val,
                                                        const int* __restrict__ perm,
                                                        const float* __restrict__ dinv,
                                                        const float* __restrict__ b,
                                                        uint2* __restrict__ out,
                                                        const int* __restrict__ batch,
                                                        float* __restrict__ gpool, int n) {
    unsigned t = blockIdx.x * 256 + threadIdx.x;
    unsigned j = t / (unsigned)TPN, q = t % (unsigned)TPN;
    if (j >= (unsigned)n) return;
    unsigned i = (unsigned)perm[j];

    float dv = dinv[i];
    float s = dv * dv;
    float4 self = h4_to_f4(xwh[i * TPN + q]);
    float4 acc = make_float4(s * self.x, s * self.y, s * self.z, s * self.w);
    if (BIAS) {
        float4 bb = reinterpret_cast<const float4*>(b)[q];
        acc.x += bb.x; acc.y += bb.y; acc.z += bb.z; acc.w += bb.w;
    }

    int e = rowptr[j], end = rowptr[j + 1];
    for (; e < end; e += 8) {
        int4 ca = *reinterpret_cast<const int4*>(col + e);
        int4 cb = *reinterpret_cast<const int4*>(col + e + 4);
        float4 wa = *reinterpret_cast<const float4*>(val + e);
        float4 wb = *reinterpret_cast<const float4*>(val + e + 4);
        uint2 u0 = xwh[(unsigned)ca.x * TPN + q];
        uint2 u1 = xwh[(unsigned)ca.y * TPN + q];
        uint2 u2 = xwh[(unsigned)ca.z * TPN + q];
        uint2 u3 = xwh[(unsigned)ca.w * TPN + q];
        uint2 u4 = xwh[(unsigned)cb.x * TPN + q];
        uint2 u5 = xwh[(unsigned)cb.y * TPN + q];
        uint2 u6 = xwh[(unsigned)cb.z * TPN + q];
        uint2 u7 = xwh[(unsigned)cb.w * TPN + q];
        float4 v0 = h4_to_f4(u0), v1 = h4_to_f4(u1);
        float4 v2 = h4_to_f4(u2), v3 = h4_to_f4(u3);
        float4 v4 = h4_to_f4(u4), v5 = h4_to_f4(u5);
        float4 v6 = h4_to_f4(u6), v7 = h4_to_f4(u7);
        acc.x += wa.x * v0.x + wa.y * v1.x + wa.z * v2.x + wa.w * v3.x
               + wb.x * v4.x + wb.y * v5.x + wb.z * v6.x + wb.w * v7.x;
        acc.y += wa.x * v0.y + wa.y * v1.y + wa.z * v2.y + wa.w * v3.y
               + wb.x * v4.y + wb.y * v5.y + wb.z * v6.y + wb.w * v7.y;
        acc.z += wa.x * v0.z + wa.y * v1.z + wa.z * v2.z + wa.w * v3.z
               + wb.x * v4.z + wb.y * v5.z + wb.z * v6.z + wb.w * v7.z;
        acc.w += wa.x * v0.w + wa.y * v1.w + wa.z * v2.w + wa.w * v3.w
               + wb.x * v4.w + wb.y * v5.w + wb.z * v6.w + wb.w * v7.w;
    }

    if (POOL) {
        float* o = gpool + (size_t)batch[i] * (TPN * 4);
        unsigned fo = q * 4u;
        atomicAdd(o + fo + 0, fmaxf(acc.x, 0.f));
        atomicAdd(o + fo + 1, fmaxf(acc.y, 0.f));
        atomicAdd(o + fo + 2, fmaxf(acc.z, 0.f));
        atomicAdd(o + fo + 3, fmaxf(acc.w, 0.f));
    } else {
        out[i * TPN + q] = f4_to_h4(acc);
    }
}

__global__ __launch_bounds__(64) void mlp_kernel(const float* __restrict__ g,
                                                 const float* __restrict__ Wf1,
                                                 const float* __restrict__ bf1,
                                                 const float* __restrict__ Wf2,
                                                 const float* __restrict__ bf2,
                                                 float* __restrict__ out, int G) {
    __shared__ float gs[HIDDEN];
    __shared__ float hid[32];
    int blk = blockIdx.x;
    int lane = threadIdx.x;
    for (int idx = lane; idx < HIDDEN; idx += 64) gs[idx] = g[(size_t)blk * HIDDEN + idx];
    __syncthreads();
    if (lane < 32) {
        float a = bf1[lane];
        for (int k = 0; k < HIDDEN; k++) a = fmaf(gs[k], Wf1[k * 32 + lane], a);
        hid[lane] = fmaxf(a, 0.f);
    }
    __syncthreads();
    if (lane == 0) {
        float o = bf2[0];
        for (int k = 0; k < 32; k++) o = fmaf(hid[k], Wf2[k], o);
        out[blk] = o;
    }
}

extern "C" void kernel_launch(void* const* d_in, const int* in_sizes, int n_in,
                              void* d_out, int out_size, void* d_ws, size_t ws_size,
                              hipStream_t stream) {
    const float* x     = (const float*)d_in[0];
    const int*   ei    = (const int*)d_in[1];
    const int*   batch = (const int*)d_in[2];
    const float* W1 = (const float*)d_in[3];  const float* b1 = (const float*)d_in[4];
    const float* W2 = (const float*)d_in[5];  const float* b2 = (const float*)d_in[6];
    const float* W3 = (const float*)d_in[7];  const float* b3 = (const float*)d_in[8];
    const float* W4 = (const float*)d_in[9];  const float* b4 = (const float*)d_in[10];
    const float* Wf1 = (const float*)d_in[11]; const float* bf1 = (const float*)d_in[12];
    const float* Wf2 = (const float*)d_in[13]; const float* bf2 = (const float*)d_in[14];
    float* out = (float*)d_out;

    int N = in_sizes[0] / 32;   // 100000
    int E = in_sizes[1] / 2;    // 1600000
    int G = out_size;           // 2048
    const int* src = ei;
    const int* dst = ei + E;
    int Emax = E + 8 * N;       // pad8-CSR upper bound (2.4M)

    // Workspace layout (~82 MB)
    char* ws = (char*)d_ws;
    size_t off = 0;
    auto alloc = [&](size_t bytes) -> void* {
        void* p = (void*)(ws + off);
        off += (bytes + 255) & ~(size_t)255;
        return p;
    };
    int*   degcnt = (int*)alloc((size_t)N * 4);
    float* dinv   = (float*)alloc((size_t)N * 4);
    int*   rowptr = (int*)alloc((size_t)(N + 1) * 4);
    int*   bsum   = (int*)alloc((size_t)128 * 4);
    int*   hist   = (int*)alloc((size_t)64 * 4);
    int*   hbase  = (int*)alloc((size_t)64 * 4);
    int*   mypos  = (int*)alloc((size_t)N * 4);
    int*   rankb  = (int*)alloc((size_t)N * 4);
    int*   perm   = (int*)alloc((size_t)N * 4);
    int*   col    = (int*)alloc((size_t)Emax * 4);
    float* val    = (float*)alloc((size_t)Emax * 4);
    int*   epos   = (int*)alloc((size_t)E * 4);
    uint2* xh     = (uint2*)alloc((size_t)N * 32 * 2);      // x fp16
    uint2* aggXh  = (uint2*)alloc((size_t)N * 32 * 2);      // (A x) fp16
    uint2* bufB   = (uint2*)alloc((size_t)N * HIDDEN * 2);  // h fp16
    uint2* bufH   = (uint2*)alloc((size_t)N * HIDDEN * 2);  // xw fp16
    float* gbuf   = (float*)alloc((size_t)G * HIDDEN * 4);
    (void)ws_size;

    int gN   = (N + 255) / 256;
    int gE   = (E + 255) / 256;
    int gEm  = (Emax + 255) / 256;
    int gAgg32 = (int)(((long long)N * 8 + 255) / 256);
    int gAgg96 = (int)(((long long)N * 24 + 255) / 256);
    int nb   = (N + 1023) / 1024;   // 98 scan blocks (<= 128)

    // ---- CSR build, degree-sorted (once per call) ----
    zero_int_kernel<<<gN, 256, 0, stream>>>(degcnt, N);
    zero_int_kernel<<<1, 256, 0, stream>>>(hist, 64);
    zero_int_kernel<<<gEm, 256, 0, stream>>>(col, Emax);
    zero_kernel<<<gEm, 256, 0, stream>>>(val, Emax);
    deg_pos_kernel<<<gE, 256, 0, stream>>>(dst, degcnt, epos, E);
    dinv_kernel<<<gN, 256, 0, stream>>>(degcnt, dinv, N);
    bucket_kernel<<<gN, 256, 0, stream>>>(degcnt, hist, mypos, N);
    hist_scan_kernel<<<1, 64, 0, stream>>>(hist, hbase);
    rank_kernel<<<gN, 256, 0, stream>>>(degcnt, hbase, mypos, rankb, perm, N);
    scan_reduce_kernel<<<nb, 256, 0, stream>>>(degcnt, perm, bsum, N);
    scan_bsum_kernel<<<1, 128, 0, stream>>>(bsum, nb);
    scan_write_kernel<<<nb, 256, 0, stream>>>(degcnt, perm, bsum, rowptr, N);
    fill_csr_kernel<<<gE, 256, 0, stream>>>(src, dst, epos, rankb, dinv, rowptr, col, val, E);

    // ---- layer 1 reassociated: aggX = A x (32 feats), h1 = aggX W1 + b1 ----
    cast_h_kernel<<<(N * 8 + 255) / 256, 256, 0, stream>>>(
        reinterpret_cast<const float4*>(x), xh, N * 8);
    aggregate_kernel<8, false, false><<<gAgg32, 256, 0, stream>>>(
        xh, rowptr, col, val, perm, dinv, nullptr, aggXh, nullptr, nullptr, N);
    gemm_kernel<32, false, true><<<gN, 256, 0, stream>>>(aggXh, W1, b1, bufB, N);

    // ---- layers 2-3: xw = relu(h) W (fp16); h' = A xw + b (fp16) ----
    gemm_kernel<96, true, false><<<gN, 256, 0, stream>>>(bufB, W2, nullptr, bufH, N);
    aggregate_kernel<24, false, true><<<gAgg96, 256, 0, stream>>>(
        bufH, rowptr, col, val, perm, dinv, b2, bufB, nullptr, nullptr, N);

    gemm_kernel<96, true, false><<<gN, 256, 0, stream>>>(bufB, W3, nullptr, bufH, N);
    aggregate_kernel<24, false, true><<<gAgg96, 256, 0, stream>>>(
        bufH, rowptr, col, val, perm, dinv, b3, bufB, nullptr, nullptr, N);

    // ---- layer 4: aggregate fused with relu + global_add_pool (fp32) ----
    zero_kernel<<<(G * HIDDEN + 255) / 256, 256, 0, stream>>>(gbuf, G * HIDDEN);
    gemm_kernel<96, true, false><<<gN, 256, 0, stream>>>(bufB, W4, nullptr, bufH, N);
    aggregate_kernel<24, true, true><<<gAgg96, 256, 0, stream>>>(
        bufH, rowptr, col, val, perm, dinv, b4, nullptr, batch, gbuf, N);

    // ---- MLP head ----
    mlp_kernel<<<G, 64, 0, stream>>>(gbuf, Wf1, bf1, Wf2, bf2, out, G);
}

// Round 9
// 758.073 us; speedup vs baseline: 1.9272x; 1.9272x over previous
//
#include <hip/hip_runtime.h>
#include <hip/hip_fp16.h>

// GCN: 4x GCNConv(relu) -> global_add_pool -> MLP(96->32 relu ->1)
// N=100000 nodes, E=1600000 edges, F=32, H=96, G=2048 graphs.
//
// R9: R8's degree-sorted CSR kept, but bucket histogram is now hierarchical:
// per-block LDS histogram + one global atomic per (block,bucket). R8's flat
// version did 100k atomics onto 64 global addresses = 748 us of contention.
// Aggregate: TPN=24, uint2 lanes, pad8 rows, 8-way unroll (R6 sweet spot).

#define HIDDEN 96

__device__ inline float4 h4_to_f4(uint2 u) {
    __half2 a = *reinterpret_cast<__half2*>(&u.x);
    __half2 b = *reinterpret_cast<__half2*>(&u.y);
    float2 fa = __half22float2(a), fb = __half22float2(b);
    return make_float4(fa.x, fa.y, fb.x, fb.y);
}

__device__ inline uint2 f4_to_h4(float4 v) {
    __half2 a = __float22half2_rn(make_float2(v.x, v.y));
    __half2 b = __float22half2_rn(make_float2(v.z, v.w));
    uint2 u;
    u.x = *reinterpret_cast<unsigned*>(&a);
    u.y = *reinterpret_cast<unsigned*>(&b);
    return u;
}

__device__ inline int pad8i(int c) { return (c + 7) & ~7; }

__global__ __launch_bounds__(256) void zero_int_kernel(int* p, int n) {
    int i = blockIdx.x * 256 + threadIdx.x;
    if (i < n) p[i] = 0;
}

__global__ __launch_bounds__(256) void zero_kernel(float* p, int n) {
    int i = blockIdx.x * 256 + threadIdx.x;
    if (i < n) p[i] = 0.0f;
}

__global__ __launch_bounds__(256) void cast_h_kernel(const float4* __restrict__ in,
                                                     uint2* __restrict__ out, int n4) {
    int i = blockIdx.x * 256 + threadIdx.x;
    if (i < n4) out[i] = f4_to_h4(in[i]);
}

// in-degree histogram over dst; epos[e] = this edge's slot within its dst row
__global__ __launch_bounds__(256) void deg_pos_kernel(const int* __restrict__ dst,
                                                      int* __restrict__ cnt,
                                                      int* __restrict__ epos, int E) {
    int e = blockIdx.x * 256 + threadIdx.x;
    if (e < E) epos[e] = atomicAdd(&cnt[dst[e]], 1);
}

__global__ __launch_bounds__(256) void dinv_kernel(const int* __restrict__ cnt,
                                                   float* __restrict__ dinv, int n) {
    int i = blockIdx.x * 256 + threadIdx.x;
    if (i < n) dinv[i] = rsqrtf((float)(cnt[i] + 1));
}

// ---- degree bucket sort (64 buckets of padded-degree/8) ----
// Hierarchical: LDS histogram per block, ONE global atomic per (block,bucket).
// R8's flat version (100k atomics -> 64 addresses) cost 748 us.
__global__ __launch_bounds__(256) void bucket_kernel(const int* __restrict__ cnt,
                                                     int* __restrict__ hist,
                                                     int* __restrict__ mypos, int N) {
    __shared__ int lhist[64];
    __shared__ int lbase[64];
    int tid = threadIdx.x;
    if (tid < 64) lhist[tid] = 0;
    __syncthreads();
    int i = blockIdx.x * 256 + tid;
    int k = 0, lpos = 0;
    bool valid = (i < N);
    if (valid) {
        k = min(pad8i(cnt[i]) >> 3, 63);
        lpos = atomicAdd(&lhist[k], 1);
    }
    __syncthreads();
    if (tid < 64) {
        int c = lhist[tid];
        lbase[tid] = (c > 0) ? atomicAdd(&hist[tid], c) : 0;
    }
    __syncthreads();
    if (valid) mypos[i] = lbase[k] + lpos;
}

// exclusive scan of hist[0..64) in one wave
__global__ __launch_bounds__(64) void hist_scan_kernel(const int* __restrict__ hist,
                                                       int* __restrict__ base) {
    int tid = threadIdx.x;
    int h = hist[tid];
    int v = h;
    for (int off = 1; off < 64; off <<= 1) {
        int t = __shfl_up(v, off);
        if (tid >= off) v += t;
    }
    base[tid] = v - h;  // exclusive
}

__global__ __launch_bounds__(256) void rank_kernel(const int* __restrict__ cnt,
                                                   const int* __restrict__ base,
                                                   const int* __restrict__ mypos,
                                                   int* __restrict__ rank,
                                                   int* __restrict__ perm, int N) {
    int i = blockIdx.x * 256 + threadIdx.x;
    if (i >= N) return;
    int k = min(pad8i(cnt[i]) >> 3, 63);
    int r = base[k] + mypos[i];
    rank[i] = r;
    perm[r] = i;
}

// ---- 3-phase exclusive scan of pad8(cnt[perm[0..N)]) -> rowptr ----
__global__ __launch_bounds__(256) void scan_reduce_kernel(const int* __restrict__ cnt,
                                                          const int* __restrict__ perm,
                                                          int* __restrict__ bsum, int N) {
    __shared__ int s[256];
    int b = blockIdx.x, tid = threadIdx.x;
    int basei = b * 1024;
    int v = 0;
    for (int j = tid; j < 1024; j += 256) {
        int i = basei + j;
        v += (i < N) ? pad8i(cnt[perm[i]]) : 0;
    }
    s[tid] = v;
    __syncthreads();
    for (int off = 128; off > 0; off >>= 1) {
        if (tid < off) s[tid] += s[tid + off];
        __syncthreads();
    }
    if (tid == 0) bsum[b] = s[0];
}

__global__ __launch_bounds__(128) void scan_bsum_kernel(int* __restrict__ bsum, int nb) {
    __shared__ int s[128];
    int tid = threadIdx.x;
    int v = (tid < nb) ? bsum[tid] : 0;
    s[tid] = v;
    __syncthreads();
    for (int off = 1; off < 128; off <<= 1) {
        int t = (tid >= off) ? s[tid - off] : 0;
        __syncthreads();
        s[tid] += t;
        __syncthreads();
    }
    if (tid < nb) bsum[tid] = s[tid] - v;  // exclusive
}

__global__ __launch_bounds__(256) void scan_write_kernel(const int* __restrict__ cnt,
                                                         const int* __restrict__ perm,
                                                         const int* __restrict__ bsum,
                                                         int* __restrict__ rowptr, int N) {
    __shared__ int ts[256];
    int b = blockIdx.x, tid = threadIdx.x;
    int basei = b * 1024 + tid * 4;
    int v0 = (basei + 0 < N) ? pad8i(cnt[perm[basei + 0]]) : 0;
    int v1 = (basei + 1 < N) ? pad8i(cnt[perm[basei + 1]]) : 0;
    int v2 = (basei + 2 < N) ? pad8i(cnt[perm[basei + 2]]) : 0;
    int v3 = (basei + 3 < N) ? pad8i(cnt[perm[basei + 3]]) : 0;
    int sum = v0 + v1 + v2 + v3;
    ts[tid] = sum;
    __syncthreads();
    for (int off = 1; off < 256; off <<= 1) {
        int t = (tid >= off) ? ts[tid - off] : 0;
        __syncthreads();
        ts[tid] += t;
        __syncthreads();
    }
    int excl = bsum[b] + ts[tid] - sum;
    if (basei + 0 <= N) rowptr[basei + 0] = excl;
    if (basei + 1 <= N) rowptr[basei + 1] = excl + v0;
    if (basei + 2 <= N) rowptr[basei + 2] = excl + v0 + v1;
    if (basei + 3 <= N) rowptr[basei + 3] = excl + v0 + v1 + v2;
}

// Fill CSR slots in degree-sorted row order.
__global__ __launch_bounds__(256) void fill_csr_kernel(const int* __restrict__ src,
                                                       const int* __restrict__ dst,
                                                       const int* __restrict__ epos,
                                                       const int* __restrict__ rank,
                                                       const float* __restrict__ dinv,
                                                       const int* __restrict__ rowptr,
                                                       int* __restrict__ col,
                                                       float* __restrict__ val, int E) {
    int e = blockIdx.x * 256 + threadIdx.x;
    if (e >= E) return;
    int s = src[e];
    int d = dst[e];
    int idx = rowptr[rank[d]] + epos[e];
    col[idx] = s;
    val[idx] = dinv[s] * dinv[d];
}

// Y[n x 96] = act(X[n x K]) @ W[K x 96] (+ b).  W in LDS, fp16 in/out.
template <int K, bool RELU, bool BIAS>
__global__ __launch_bounds__(256) void gemm_kernel(const uint2* __restrict__ X,
                                                   const float* __restrict__ W,
                                                   const float* __restrict__ b,
                                                   uint2* __restrict__ Y, int n) {
    __shared__ float wlds[K * HIDDEN];
    for (int idx = threadIdx.x; idx < K * HIDDEN; idx += 256) wlds[idx] = W[idx];
    __syncthreads();

    int row = blockIdx.x * 256 + threadIdx.x;
    if (row >= n) return;

    float4 acc[24];
#pragma unroll
    for (int j = 0; j < 24; j++) acc[j] = make_float4(0.f, 0.f, 0.f, 0.f);

    const float4* wl4 = reinterpret_cast<const float4*>(wlds);
    const uint2* xrow = X + (size_t)row * (K / 4);

    for (int k0 = 0; k0 < K; k0 += 4) {
        float4 xv = h4_to_f4(xrow[k0 >> 2]);
        if (RELU) {
            xv.x = fmaxf(xv.x, 0.f); xv.y = fmaxf(xv.y, 0.f);
            xv.z = fmaxf(xv.z, 0.f); xv.w = fmaxf(xv.w, 0.f);
        }
#pragma unroll
        for (int kk = 0; kk < 4; kk++) {
            float xs = (kk == 0) ? xv.x : (kk == 1) ? xv.y : (kk == 2) ? xv.z : xv.w;
#pragma unroll
            for (int j = 0; j < 24; j++) {
                float4 w = wl4[(k0 + kk) * 24 + j];
                acc[j].x += xs * w.x;
                acc[j].y += xs * w.y;
                acc[j].z += xs * w.z;
                acc[j].w += xs * w.w;
            }
        }
    }

    uint2* y2 = Y + (size_t)row * 24;
#pragma unroll
    for (int j = 0; j < 24; j++) {
        if (BIAS) {
            float4 bb = reinterpret_cast<const float4*>(b)[j];
            acc[j].x += bb.x; acc[j].y += bb.y; acc[j].z += bb.z; acc[j].w += bb.w;
        }
        y2[j] = f4_to_h4(acc[j]);
    }
}

// Degree-sorted aggregate: sorted position j -> node i = perm[j].
// out[i] = dinv[i]^2*xw[i] (+ b) + sum_e val[e]*xw[col[e]], xw fp16.
// TPN threads/node (4 feats = uint2 8B per lane), rows padded to 8,
// 8-way unroll. fp32 accumulate. POOL: atomicAdd relu into gpool[batch[i]].
template <int TPN, bool POOL, bool BIAS>
__global__ __launch_bounds__(256) void aggregate_kernel(const uint2* __restrict__ xwh,
                                                        const int* __restrict__ rowptr,
                                                        const int* __restrict__ col,
                                                        const float* __restrict__ val,
                                                        const int* __restrict__ perm,
                                                        const float* __restrict__ dinv,
                                                        const float* __restrict__ b,
                                                        uint2* __restrict__ out,
                                                        const int* __restrict__ batch,
                                                        float* __restrict__ gpool, int n) {
    unsigned t = blockIdx.x * 256 + threadIdx.x;
    unsigned j = t / (unsigned)TPN, q = t % (unsigned)TPN;
    if (j >= (unsigned)n) return;
    unsigned i = (unsigned)perm[j];

    float dv = dinv[i];
    float s = dv * dv;
    float4 self = h4_to_f4(xwh[i * TPN + q]);
    float4 acc = make_float4(s * self.x, s * self.y, s * self.z, s * self.w);
    if (BIAS) {
        float4 bb = reinterpret_cast<const float4*>(b)[q];
        acc.x += bb.x; acc.y += bb.y; acc.z += bb.z; acc.w += bb.w;
    }

    int e = rowptr[j], end = rowptr[j + 1];
    for (; e < end; e += 8) {
        int4 ca = *reinterpret_cast<const int4*>(col + e);
        int4 cb = *reinterpret_cast<const int4*>(col + e + 4);
        float4 wa = *reinterpret_cast<const float4*>(val + e);
        float4 wb = *reinterpret_cast<const float4*>(val + e + 4);
        uint2 u0 = xwh[(unsigned)ca.x * TPN + q];
        uint2 u1 = xwh[(unsigned)ca.y * TPN + q];
        uint2 u2 = xwh[(unsigned)ca.z * TPN + q];
        uint2 u3 = xwh[(unsigned)ca.w * TPN + q];
        uint2 u4 = xwh[(unsigned)cb.x * TPN + q];
        uint2 u5 = xwh[(unsigned)cb.y * TPN + q];
        uint2 u6 = xwh[(unsigned)cb.z * TPN + q];
        uint2 u7 = xwh[(unsigned)cb.w * TPN + q];
        float4 v0 = h4_to_f4(u0), v1 = h4_to_f4(u1);
        float4 v2 = h4_to_f4(u2), v3 = h4_to_f4(u3);
        float4 v4 = h4_to_f4(u4), v5 = h4_to_f4(u5);
        float4 v6 = h4_to_f4(u6), v7 = h4_to_f4(u7);
        acc.x += wa.x * v0.x + wa.y * v1.x + wa.z * v2.x + wa.w * v3.x
               + wb.x * v4.x + wb.y * v5.x + wb.z * v6.x + wb.w * v7.x;
        acc.y += wa.x * v0.y + wa.y * v1.y + wa.z * v2.y + wa.w * v3.y
               + wb.x * v4.y + wb.y * v5.y + wb.z * v6.y + wb.w * v7.y;
        acc.z += wa.x * v0.z + wa.y * v1.z + wa.z * v2.z + wa.w * v3.z
               + wb.x * v4.z + wb.y * v5.z + wb.z * v6.z + wb.w * v7.z;
        acc.w += wa.x * v0.w + wa.y * v1.w + wa.z * v2.w + wa.w * v3.w
               + wb.x * v4.w + wb.y * v5.w + wb.z * v6.w + wb.w * v7.w;
    }

    if (POOL) {
        float* o = gpool + (size_t)batch[i] * (TPN * 4);
        unsigned fo = q * 4u;
        atomicAdd(o + fo + 0, fmaxf(acc.x, 0.f));
        atomicAdd(o + fo + 1, fmaxf(acc.y, 0.f));
        atomicAdd(o + fo + 2, fmaxf(acc.z, 0.f));
        atomicAdd(o + fo + 3, fmaxf(acc.w, 0.f));
    } else {
        out[i * TPN + q] = f4_to_h4(acc);
    }
}

__global__ __launch_bounds__(64) void mlp_kernel(const float* __restrict__ g,
                                                 const float* __restrict__ Wf1,
                                                 const float* __restrict__ bf1,
                                                 const float* __restrict__ Wf2,
                                                 const float* __restrict__ bf2,
                                                 float* __restrict__ out, int G) {
    __shared__ float gs[HIDDEN];
    __shared__ float hid[32];
    int blk = blockIdx.x;
    int lane = threadIdx.x;
    for (int idx = lane; idx < HIDDEN; idx += 64) gs[idx] = g[(size_t)blk * HIDDEN + idx];
    __syncthreads();
    if (lane < 32) {
        float a = bf1[lane];
        for (int k = 0; k < HIDDEN; k++) a = fmaf(gs[k], Wf1[k * 32 + lane], a);
        hid[lane] = fmaxf(a, 0.f);
    }
    __syncthreads();
    if (lane == 0) {
        float o = bf2[0];
        for (int k = 0; k < 32; k++) o = fmaf(hid[k], Wf2[k], o);
        out[blk] = o;
    }
}

extern "C" void kernel_launch(void* const* d_in, const int* in_sizes, int n_in,
                              void* d_out, int out_size, void* d_ws, size_t ws_size,
                              hipStream_t stream) {
    const float* x     = (const float*)d_in[0];
    const int*   ei    = (const int*)d_in[1];
    const int*   batch = (const int*)d_in[2];
    const float* W1 = (const float*)d_in[3];  const float* b1 = (const float*)d_in[4];
    const float* W2 = (const float*)d_in[5];  const float* b2 = (const float*)d_in[6];
    const float* W3 = (const float*)d_in[7];  const float* b3 = (const float*)d_in[8];
    const float* W4 = (const float*)d_in[9];  const float* b4 = (const float*)d_in[10];
    const float* Wf1 = (const float*)d_in[11]; const float* bf1 = (const float*)d_in[12];
    const float* Wf2 = (const float*)d_in[13]; const float* bf2 = (const float*)d_in[14];
    float* out = (float*)d_out;

    int N = in_sizes[0] / 32;   // 100000
    int E = in_sizes[1] / 2;    // 1600000
    int G = out_size;           // 2048
    const int* src = ei;
    const int* dst = ei + E;
    int Emax = E + 8 * N;       // pad8-CSR upper bound (2.4M)

    // Workspace layout (~82 MB)
    char* ws = (char*)d_ws;
    size_t off = 0;
    auto alloc = [&](size_t bytes) -> void* {
        void* p = (void*)(ws + off);
        off += (bytes + 255) & ~(size_t)255;
        return p;
    };
    int*   degcnt = (int*)alloc((size_t)N * 4);
    float* dinv   = (float*)alloc((size_t)N * 4);
    int*   rowptr = (int*)alloc((size_t)(N + 1) * 4);
    int*   bsum   = (int*)alloc((size_t)128 * 4);
    int*   hist   = (int*)alloc((size_t)64 * 4);
    int*   hbase  = (int*)alloc((size_t)64 * 4);
    int*   mypos  = (int*)alloc((size_t)N * 4);
    int*   rankb  = (int*)alloc((size_t)N * 4);
    int*   perm   = (int*)alloc((size_t)N * 4);
    int*   col    = (int*)alloc((size_t)Emax * 4);
    float* val    = (float*)alloc((size_t)Emax * 4);
    int*   epos   = (int*)alloc((size_t)E * 4);
    uint2* xh     = (uint2*)alloc((size_t)N * 32 * 2);      // x fp16
    uint2* aggXh  = (uint2*)alloc((size_t)N * 32 * 2);      // (A x) fp16
    uint2* bufB   = (uint2*)alloc((size_t)N * HIDDEN * 2);  // h fp16
    uint2* bufH   = (uint2*)alloc((size_t)N * HIDDEN * 2);  // xw fp16
    float* gbuf   = (float*)alloc((size_t)G * HIDDEN * 4);
    (void)ws_size;

    int gN   = (N + 255) / 256;
    int gE   = (E + 255) / 256;
    int gEm  = (Emax + 255) / 256;
    int gAgg32 = (int)(((long long)N * 8 + 255) / 256);
    int gAgg96 = (int)(((long long)N * 24 + 255) / 256);
    int nb   = (N + 1023) / 1024;   // 98 scan blocks (<= 128)

    // ---- CSR build, degree-sorted (once per call) ----
    zero_int_kernel<<<gN, 256, 0, stream>>>(degcnt, N);
    zero_int_kernel<<<1, 256, 0, stream>>>(hist, 64);
    zero_int_kernel<<<gEm, 256, 0, stream>>>(col, Emax);
    zero_kernel<<<gEm, 256, 0, stream>>>(val, Emax);
    deg_pos_kernel<<<gE, 256, 0, stream>>>(dst, degcnt, epos, E);
    dinv_kernel<<<gN, 256, 0, stream>>>(degcnt, dinv, N);
    bucket_kernel<<<gN, 256, 0, stream>>>(degcnt, hist, mypos, N);
    hist_scan_kernel<<<1, 64, 0, stream>>>(hist, hbase);
    rank_kernel<<<gN, 256, 0, stream>>>(degcnt, hbase, mypos, rankb, perm, N);
    scan_reduce_kernel<<<nb, 256, 0, stream>>>(degcnt, perm, bsum, N);
    scan_bsum_kernel<<<1, 128, 0, stream>>>(bsum, nb);
    scan_write_kernel<<<nb, 256, 0, stream>>>(degcnt, perm, bsum, rowptr, N);
    fill_csr_kernel<<<gE, 256, 0, stream>>>(src, dst, epos, rankb, dinv, rowptr, col, val, E);

    // ---- layer 1 reassociated: aggX = A x (32 feats), h1 = aggX W1 + b1 ----
    cast_h_kernel<<<(N * 8 + 255) / 256, 256, 0, stream>>>(
        reinterpret_cast<const float4*>(x), xh, N * 8);
    aggregate_kernel<8, false, false><<<gAgg32, 256, 0, stream>>>(
        xh, rowptr, col, val, perm, dinv, nullptr, aggXh, nullptr, nullptr, N);
    gemm_kernel<32, false, true><<<gN, 256, 0, stream>>>(aggXh, W1, b1, bufB, N);

    // ---- layers 2-3: xw = relu(h) W (fp16); h' = A xw + b (fp16) ----
    gemm_kernel<96, true, false><<<gN, 256, 0, stream>>>(bufB, W2, nullptr, bufH, N);
    aggregate_kernel<24, false, true><<<gAgg96, 256, 0, stream>>>(
        bufH, rowptr, col, val, perm, dinv, b2, bufB, nullptr, nullptr, N);

    gemm_kernel<96, true, false><<<gN, 256, 0, stream>>>(bufB, W3, nullptr, bufH, N);
    aggregate_kernel<24, false, true><<<gAgg96, 256, 0, stream>>>(
        bufH, rowptr, col, val, perm, dinv, b3, bufB, nullptr, nullptr, N);

    // ---- layer 4: aggregate fused with relu + global_add_pool (fp32) ----
    zero_kernel<<<(G * HIDDEN + 255) / 256, 256, 0, stream>>>(gbuf, G * HIDDEN);
    gemm_kernel<96, true, false><<<gN, 256, 0, stream>>>(bufB, W4, nullptr, bufH, N);
    aggregate_kernel<24, true, true><<<gAgg96, 256, 0, stream>>>(
        bufH, rowptr, col, val, perm, dinv, b4, nullptr, batch, gbuf, N);

    // ---- MLP head ----
    mlp_kernel<<<G, 64, 0, stream>>>(gbuf, Wf1, bf1, Wf2, bf2, out, G);
}

// Round 10
// 694.893 us; speedup vs baseline: 2.1025x; 1.0909x over previous
//
#include <hip/hip_runtime.h>
#include <hip/hip_fp16.h>

// GCN: 4x GCNConv(relu) -> global_add_pool -> MLP(96->32 relu ->1)
// N=100000 nodes, E=1600000 edges, F=32, H=96, G=2048 graphs.
//
// R10: revert R8/R9 degree-sort (regressed: perm-scatter cost > trip-waste
// saving). Back to R6 structure: natural node order, TPN=24 x uint2 fp16
// gathers (measured sweet spot), fp16 inter-layer buffers, layer-1
// reassociation, layer-4 agg+relu+pool fusion. Change vs R6: pad4 rows +
// 4-way unroll (mean padded row 19.9 -> 17.9 slots, -10% edge-slot work).

#define HIDDEN 96

__device__ inline float4 h4_to_f4(uint2 u) {
    __half2 a = *reinterpret_cast<__half2*>(&u.x);
    __half2 b = *reinterpret_cast<__half2*>(&u.y);
    float2 fa = __half22float2(a), fb = __half22float2(b);
    return make_float4(fa.x, fa.y, fb.x, fb.y);
}

__device__ inline uint2 f4_to_h4(float4 v) {
    __half2 a = __float22half2_rn(make_float2(v.x, v.y));
    __half2 b = __float22half2_rn(make_float2(v.z, v.w));
    uint2 u;
    u.x = *reinterpret_cast<unsigned*>(&a);
    u.y = *reinterpret_cast<unsigned*>(&b);
    return u;
}

__device__ inline int pad4i(int c) { return (c + 3) & ~3; }

__global__ __launch_bounds__(256) void zero_int_kernel(int* p, int n) {
    int i = blockIdx.x * 256 + threadIdx.x;
    if (i < n) p[i] = 0;
}

__global__ __launch_bounds__(256) void zero_kernel(float* p, int n) {
    int i = blockIdx.x * 256 + threadIdx.x;
    if (i < n) p[i] = 0.0f;
}

__global__ __launch_bounds__(256) void cast_h_kernel(const float4* __restrict__ in,
                                                     uint2* __restrict__ out, int n4) {
    int i = blockIdx.x * 256 + threadIdx.x;
    if (i < n4) out[i] = f4_to_h4(in[i]);
}

// in-degree histogram over dst; epos[e] = this edge's slot within its dst row
__global__ __launch_bounds__(256) void deg_pos_kernel(const int* __restrict__ dst,
                                                      int* __restrict__ cnt,
                                                      int* __restrict__ epos, int E) {
    int e = blockIdx.x * 256 + threadIdx.x;
    if (e < E) epos[e] = atomicAdd(&cnt[dst[e]], 1);
}

__global__ __launch_bounds__(256) void dinv_kernel(const int* __restrict__ cnt,
                                                   float* __restrict__ dinv, int n) {
    int i = blockIdx.x * 256 + threadIdx.x;
    if (i < n) dinv[i] = rsqrtf((float)(cnt[i] + 1));
}

// ---- 3-phase multi-block exclusive scan of pad4(cnt[0..N)) -> rowptr ----
__global__ __launch_bounds__(256) void scan_reduce_kernel(const int* __restrict__ cnt,
                                                          int* __restrict__ bsum, int N) {
    __shared__ int s[256];
    int b = blockIdx.x, tid = threadIdx.x;
    int base = b * 1024;
    int v = 0;
    for (int j = tid; j < 1024; j += 256) {
        int i = base + j;
        v += (i < N) ? pad4i(cnt[i]) : 0;
    }
    s[tid] = v;
    __syncthreads();
    for (int off = 128; off > 0; off >>= 1) {
        if (tid < off) s[tid] += s[tid + off];
        __syncthreads();
    }
    if (tid == 0) bsum[b] = s[0];
}

__global__ __launch_bounds__(128) void scan_bsum_kernel(int* __restrict__ bsum, int nb) {
    __shared__ int s[128];
    int tid = threadIdx.x;
    int v = (tid < nb) ? bsum[tid] : 0;
    s[tid] = v;
    __syncthreads();
    for (int off = 1; off < 128; off <<= 1) {
        int t = (tid >= off) ? s[tid - off] : 0;
        __syncthreads();
        s[tid] += t;
        __syncthreads();
    }
    if (tid < nb) bsum[tid] = s[tid] - v;  // exclusive
}

__global__ __launch_bounds__(256) void scan_write_kernel(const int* __restrict__ cnt,
                                                         const int* __restrict__ bsum,
                                                         int* __restrict__ rowptr, int N) {
    __shared__ int ts[256];
    int b = blockIdx.x, tid = threadIdx.x;
    int base = b * 1024 + tid * 4;
    int v0 = (base + 0 < N) ? pad4i(cnt[base + 0]) : 0;
    int v1 = (base + 1 < N) ? pad4i(cnt[base + 1]) : 0;
    int v2 = (base + 2 < N) ? pad4i(cnt[base + 2]) : 0;
    int v3 = (base + 3 < N) ? pad4i(cnt[base + 3]) : 0;
    int sum = v0 + v1 + v2 + v3;
    ts[tid] = sum;
    __syncthreads();
    for (int off = 1; off < 256; off <<= 1) {
        int t = (tid >= off) ? ts[tid - off] : 0;
        __syncthreads();
        ts[tid] += t;
        __syncthreads();
    }
    int excl = bsum[b] + ts[tid] - sum;
    if (base + 0 <= N) rowptr[base + 0] = excl;
    if (base + 1 <= N) rowptr[base + 1] = excl + v0;
    if (base + 2 <= N) rowptr[base + 2] = excl + v0 + v1;
    if (base + 3 <= N) rowptr[base + 3] = excl + v0 + v1 + v2;
}

// Fill CSR slots (no atomics: slot position precomputed in epos).
// Padding slots stay col=0,val=0 (pre-zeroed) -> contribute exactly 0.
__global__ __launch_bounds__(256) void fill_csr_kernel(const int* __restrict__ src,
                                                       const int* __restrict__ dst,
                                                       const int* __restrict__ epos,
                                                       const float* __restrict__ dinv,
                                                       const int* __restrict__ rowptr,
                                                       int* __restrict__ col,
                                                       float* __restrict__ val, int E) {
    int e = blockIdx.x * 256 + threadIdx.x;
    if (e >= E) return;
    int s = src[e];
    int d = dst[e];
    int idx = rowptr[d] + epos[e];
    col[idx] = s;
    val[idx] = dinv[s] * dinv[d];
}

// Y[n x 96] = act(X[n x K]) @ W[K x 96] (+ b).  W in LDS, fp16 in/out.
template <int K, bool RELU, bool BIAS>
__global__ __launch_bounds__(256) void gemm_kernel(const uint2* __restrict__ X,
                                                   const float* __restrict__ W,
                                                   const float* __restrict__ b,
                                                   uint2* __restrict__ Y, int n) {
    __shared__ float wlds[K * HIDDEN];
    for (int idx = threadIdx.x; idx < K * HIDDEN; idx += 256) wlds[idx] = W[idx];
    __syncthreads();

    int row = blockIdx.x * 256 + threadIdx.x;
    if (row >= n) return;

    float4 acc[24];
#pragma unroll
    for (int j = 0; j < 24; j++) acc[j] = make_float4(0.f, 0.f, 0.f, 0.f);

    const float4* wl4 = reinterpret_cast<const float4*>(wlds);
    const uint2* xrow = X + (size_t)row * (K / 4);

    for (int k0 = 0; k0 < K; k0 += 4) {
        float4 xv = h4_to_f4(xrow[k0 >> 2]);
        if (RELU) {
            xv.x = fmaxf(xv.x, 0.f); xv.y = fmaxf(xv.y, 0.f);
            xv.z = fmaxf(xv.z, 0.f); xv.w = fmaxf(xv.w, 0.f);
        }
#pragma unroll
        for (int kk = 0; kk < 4; kk++) {
            float xs = (kk == 0) ? xv.x : (kk == 1) ? xv.y : (kk == 2) ? xv.z : xv.w;
#pragma unroll
            for (int j = 0; j < 24; j++) {
                float4 w = wl4[(k0 + kk) * 24 + j];
                acc[j].x += xs * w.x;
                acc[j].y += xs * w.y;
                acc[j].z += xs * w.z;
                acc[j].w += xs * w.w;
            }
        }
    }

    uint2* y2 = Y + (size_t)row * 24;
#pragma unroll
    for (int j = 0; j < 24; j++) {
        if (BIAS) {
            float4 bb = reinterpret_cast<const float4*>(b)[j];
            acc[j].x += bb.x; acc[j].y += bb.y; acc[j].z += bb.z; acc[j].w += bb.w;
        }
        y2[j] = f4_to_h4(acc[j]);
    }
}

// out[i] = dinv[i]^2*xw[i] (+ b) + sum_e val[e]*xw[col[e]], xw fp16.
// TPN threads/node (4 feats = uint2 8B per lane), rows padded to 4 slots,
// 4-way unroll with aligned int4/float4 col/val loads, no remainder.
// fp32 accumulate. POOL: atomicAdd relu into gpool[batch[i]].
template <int TPN, bool POOL, bool BIAS>
__global__ __launch_bounds__(256) void aggregate_kernel(const uint2* __restrict__ xwh,
                                                        const int* __restrict__ rowptr,
                                                        const int* __restrict__ col,
                                                        const float* __restrict__ val,
                                                        const float* __restrict__ dinv,
                                                        const float* __restrict__ b,
                                                        uint2* __restrict__ out,
                                                        const int* __restrict__ batch,
                                                        float* __restrict__ gpool, int n) {
    unsigned t = blockIdx.x * 256 + threadIdx.x;
    unsigned i = t / (unsigned)TPN, q = t % (unsigned)TPN;
    if (i >= (unsigned)n) return;

    float dv = dinv[i];
    float s = dv * dv;
    float4 self = h4_to_f4(xwh[i * TPN + q]);
    float4 acc = make_float4(s * self.x, s * self.y, s * self.z, s * self.w);
    if (BIAS) {
        float4 bb = reinterpret_cast<const float4*>(b)[q];
        acc.x += bb.x; acc.y += bb.y; acc.z += bb.z; acc.w += bb.w;
    }

    int e = rowptr[i], end = rowptr[i + 1];
    for (; e < end; e += 4) {
        int4 c4 = *reinterpret_cast<const int4*>(col + e);
        float4 w4 = *reinterpret_cast<const float4*>(val + e);
        uint2 u0 = xwh[(unsigned)c4.x * TPN + q];
        uint2 u1 = xwh[(unsigned)c4.y * TPN + q];
        uint2 u2 = xwh[(unsigned)c4.z * TPN + q];
        uint2 u3 = xwh[(unsigned)c4.w * TPN + q];
        float4 v0 = h4_to_f4(u0), v1 = h4_to_f4(u1);
        float4 v2 = h4_to_f4(u2), v3 = h4_to_f4(u3);
        acc.x += w4.x * v0.x + w4.y * v1.x + w4.z * v2.x + w4.w * v3.x;
        acc.y += w4.x * v0.y + w4.y * v1.y + w4.z * v2.y + w4.w * v3.y;
        acc.z += w4.x * v0.z + w4.y * v1.z + w4.z * v2.z + w4.w * v3.z;
        acc.w += w4.x * v0.w + w4.y * v1.w + w4.z * v2.w + w4.w * v3.w;
    }

    if (POOL) {
        float* o = gpool + (size_t)batch[i] * (TPN * 4);
        unsigned fo = q * 4u;
        atomicAdd(o + fo + 0, fmaxf(acc.x, 0.f));
        atomicAdd(o + fo + 1, fmaxf(acc.y, 0.f));
        atomicAdd(o + fo + 2, fmaxf(acc.z, 0.f));
        atomicAdd(o + fo + 3, fmaxf(acc.w, 0.f));
    } else {
        out[i * TPN + q] = f4_to_h4(acc);
    }
}

__global__ __launch_bounds__(64) void mlp_kernel(const float* __restrict__ g,
                                                 const float* __restrict__ Wf1,
                                                 const float* __restrict__ bf1,
                                                 const float* __restrict__ Wf2,
                                                 const float* __restrict__ bf2,
                                                 float* __restrict__ out, int G) {
    __shared__ float gs[HIDDEN];
    __shared__ float hid[32];
    int blk = blockIdx.x;
    int lane = threadIdx.x;
    for (int idx = lane; idx < HIDDEN; idx += 64) gs[idx] = g[(size_t)blk * HIDDEN + idx];
    __syncthreads();
    if (lane < 32) {
        float a = bf1[lane];
        for (int k = 0; k < HIDDEN; k++) a = fmaf(gs[k], Wf1[k * 32 + lane], a);
        hid[lane] = fmaxf(a, 0.f);
    }
    __syncthreads();
    if (lane == 0) {
        float o = bf2[0];
        for (int k = 0; k < 32; k++) o = fmaf(hid[k], Wf2[k], o);
        out[blk] = o;
    }
}

extern "C" void kernel_launch(void* const* d_in, const int* in_sizes, int n_in,
                              void* d_out, int out_size, void* d_ws, size_t ws_size,
                              hipStream_t stream) {
    const float* x     = (const float*)d_in[0];
    const int*   ei    = (const int*)d_in[1];
    const int*   batch = (const int*)d_in[2];
    const float* W1 = (const float*)d_in[3];  const float* b1 = (const float*)d_in[4];
    const float* W2 = (const float*)d_in[5];  const float* b2 = (const float*)d_in[6];
    const float* W3 = (const float*)d_in[7];  const float* b3 = (const float*)d_in[8];
    const float* W4 = (const float*)d_in[9];  const float* b4 = (const float*)d_in[10];
    const float* Wf1 = (const float*)d_in[11]; const float* bf1 = (const float*)d_in[12];
    const float* Wf2 = (const float*)d_in[13]; const float* bf2 = (const float*)d_in[14];
    float* out = (float*)d_out;

    int N = in_sizes[0] / 32;   // 100000
    int E = in_sizes[1] / 2;    // 1600000
    int G = out_size;           // 2048
    const int* src = ei;
    const int* dst = ei + E;
    int Emax = E + 4 * N;       // pad4-CSR upper bound (2.0M)

    // Workspace layout (~72 MB)
    char* ws = (char*)d_ws;
    size_t off = 0;
    auto alloc = [&](size_t bytes) -> void* {
        void* p = (void*)(ws + off);
        off += (bytes + 255) & ~(size_t)255;
        return p;
    };
    int*   degcnt = (int*)alloc((size_t)N * 4);
    float* dinv   = (float*)alloc((size_t)N * 4);
    int*   rowptr = (int*)alloc((size_t)(N + 1) * 4);
    int*   bsum   = (int*)alloc((size_t)128 * 4);
    int*   col    = (int*)alloc((size_t)Emax * 4);
    float* val    = (float*)alloc((size_t)Emax * 4);
    int*   epos   = (int*)alloc((size_t)E * 4);
    uint2* xh     = (uint2*)alloc((size_t)N * 32 * 2);      // x fp16
    uint2* aggXh  = (uint2*)alloc((size_t)N * 32 * 2);      // (A x) fp16
    uint2* bufB   = (uint2*)alloc((size_t)N * HIDDEN * 2);  // h fp16
    uint2* bufH   = (uint2*)alloc((size_t)N * HIDDEN * 2);  // xw fp16
    float* gbuf   = (float*)alloc((size_t)G * HIDDEN * 4);
    (void)ws_size;

    int gN   = (N + 255) / 256;
    int gE   = (E + 255) / 256;
    int gEm  = (Emax + 255) / 256;
    int gAgg32 = (int)(((long long)N * 8 + 255) / 256);
    int gAgg96 = (int)(((long long)N * 24 + 255) / 256);
    int nb   = (N + 1023) / 1024;   // 98 scan blocks (<= 128)

    // ---- CSR build (once per call) ----
    zero_int_kernel<<<gN, 256, 0, stream>>>(degcnt, N);
    zero_int_kernel<<<gEm, 256, 0, stream>>>(col, Emax);
    zero_kernel<<<gEm, 256, 0, stream>>>(val, Emax);
    deg_pos_kernel<<<gE, 256, 0, stream>>>(dst, degcnt, epos, E);
    dinv_kernel<<<gN, 256, 0, stream>>>(degcnt, dinv, N);
    scan_reduce_kernel<<<nb, 256, 0, stream>>>(degcnt, bsum, N);
    scan_bsum_kernel<<<1, 128, 0, stream>>>(bsum, nb);
    scan_write_kernel<<<nb, 256, 0, stream>>>(degcnt, bsum, rowptr, N);
    fill_csr_kernel<<<gE, 256, 0, stream>>>(src, dst, epos, dinv, rowptr, col, val, E);

    // ---- layer 1 reassociated: aggX = A x (32 feats), h1 = aggX W1 + b1 ----
    cast_h_kernel<<<(N * 8 + 255) / 256, 256, 0, stream>>>(
        reinterpret_cast<const float4*>(x), xh, N * 8);
    aggregate_kernel<8, false, false><<<gAgg32, 256, 0, stream>>>(
        xh, rowptr, col, val, dinv, nullptr, aggXh, nullptr, nullptr, N);
    gemm_kernel<32, false, true><<<gN, 256, 0, stream>>>(aggXh, W1, b1, bufB, N);

    // ---- layers 2-3: xw = relu(h) W (fp16); h' = A xw + b (fp16) ----
    gemm_kernel<96, true, false><<<gN, 256, 0, stream>>>(bufB, W2, nullptr, bufH, N);
    aggregate_kernel<24, false, true><<<gAgg96, 256, 0, stream>>>(
        bufH, rowptr, col, val, dinv, b2, bufB, nullptr, nullptr, N);

    gemm_kernel<96, true, false><<<gN, 256, 0, stream>>>(bufB, W3, nullptr, bufH, N);
    aggregate_kernel<24, false, true><<<gAgg96, 256, 0, stream>>>(
        bufH, rowptr, col, val, dinv, b3, bufB, nullptr, nullptr, N);

    // ---- layer 4: aggregate fused with relu + global_add_pool (fp32) ----
    zero_kernel<<<(G * HIDDEN + 255) / 256, 256, 0, stream>>>(gbuf, G * HIDDEN);
    gemm_kernel<96, true, false><<<gN, 256, 0, stream>>>(bufB, W4, nullptr, bufH, N);
    aggregate_kernel<24, true, true><<<gAgg96, 256, 0, stream>>>(
        bufH, rowptr, col, val, dinv, b4, nullptr, batch, gbuf, N);

    // ---- MLP head ----
    mlp_kernel<<<G, 64, 0, stream>>>(gbuf, Wf1, bf1, Wf2, bf2, out, G);
}